// Round 1
// 142.265 us; speedup vs baseline: 1.0291x; 1.0291x over previous
//
#include <hip/hip_runtime.h>

// EdgeConv, algebraically simplified:
//   out[p,o] = sum_c (t[p,c]/K - x[p,c])*W[o,c] + sum_c x[p,c]*W[o,64+c] + b[o]
//   t[p,c]   = sum_{k=0..19} g_flat[p, 20c+k],  g_flat[p,j] = x[b, adj[p,j>>6], j&63]
// R6: f16 shadow copy of x (pre-pass into d_ws) -> per-batch gather working set
//     4 MB = fits one XCD L2 (batch already pinned to 2 XCDs); gather bytes halve;
//     paired-row DMAs (2 f16 rows per global_load_lds); center row stays f32 for
//     accuracy; triple-buffered DMA pipeline (vmcnt(22)) at 4 blocks/CU, GRID=1024
//     (exactly 32 iters/wave); nontemporal out store to avoid evicting xh from L2.

typedef __fp16 half2_t __attribute__((ext_vector_type(2)));
typedef __fp16 f16x4  __attribute__((ext_vector_type(4)));
typedef unsigned int u32;

#if __has_builtin(__builtin_amdgcn_fdot2)
#define FDOT2(a, b, c) __builtin_amdgcn_fdot2((a), (b), (c), false)
#else
#define FDOT2(a, b, c) fmaf((float)((a)[0]), (float)((b)[0]), fmaf((float)((a)[1]), (float)((b)[1]), (c)))
#endif

namespace {
constexpr int N_    = 32768;
constexpr int K_    = 20;
constexpr int C_    = 64;
constexpr int O_    = 64;
constexpr int BLOCK = 256;                 // 4 waves
constexpr int WPB   = 4;
constexpr int WROW  = 132;                 // padded W row stride in LDS stage

// ---- f16 pipeline config
constexpr int GRID_F16 = 1024;             // 4 blocks/CU exactly
constexpr int STAGES   = 3;                // triple-buffered DMA pipeline
constexpr int CHUNK32  = (K_ * C_ * 2 + C_ * 4) / 4;   // 704 u32 = 2816 B/stage
constexpr int WVB_F16  = (GRID_F16 / 8) * 2 * WPB;     // 1024 waves per batch
constexpr int CNT_F16  = N_ / WVB_F16;                 // 32 iters, uniform

// ---- f32 fallback (previous proven kernel) config
constexpr int GRID_F32 = 768;
constexpr int ROWS  = K_ + 1;
constexpr int WBUF  = ROWS * C_;
constexpr int WVB_F32 = (GRID_F32 / 8) * 2 * WPB;      // 768
}

// ---------------------------------------------------------------- pre-pass
__global__ __launch_bounds__(BLOCK) void cvt_f16_kernel(
    const float* __restrict__ x, __fp16* __restrict__ xh)
{
  const size_t i = ((size_t)blockIdx.x * BLOCK + threadIdx.x) * 4;
  const float4 v = *reinterpret_cast<const float4*>(x + i);
  f16x4 h;
  h[0] = (__fp16)v.x; h[1] = (__fp16)v.y; h[2] = (__fp16)v.z; h[3] = (__fp16)v.w;
  *reinterpret_cast<f16x4*>(xh + i) = h;
}

// ---------------------------------------------------------------- main (f16)
__global__ __launch_bounds__(BLOCK, 4) void edgeconv_f16_kernel(
    const float*  __restrict__ x,     // (B,N,C) f32 (center rows)
    const __fp16* __restrict__ xh,    // (B,N,C) f16 shadow (gather rows)
    const int*    __restrict__ adj,   // (B,N,K)
    const float*  __restrict__ W,     // (O, 2C)
    const float*  __restrict__ bias,  // (O,)
    float*        __restrict__ out)   // (B,N,O)
{
  __shared__ __align__(16) u32   win[WPB][STAGES][CHUNK32];  // 33792 B
  __shared__ __align__(16) float fbuf[WPB][2 * C_];          //  2048 B
  __shared__ __align__(16) u32   hbuf[WPB][C_];              //  1024 B

  const int lane = threadIdx.x & 63;
  const int wid  = __builtin_amdgcn_readfirstlane((int)(threadIdx.x >> 6));

  // ---- prologue: coalesced W -> LDS stage -> 64 packed-f16 regs per lane
  half2_t wp[64];
  {
    float* wstage = reinterpret_cast<float*>(&win[0][0][0]);   // 33772 B < 33792 B
    for (int i = threadIdx.x; i < O_ * 2 * C_; i += BLOCK)
      wstage[(i >> 7) * WROW + (i & 127)] = W[i];
    __syncthreads();
    const float2* wrow = reinterpret_cast<const float2*>(wstage + lane * WROW);
#pragma unroll
    for (int i = 0; i < 64; ++i) {
      const float2 f = wrow[i];
      wp[i] = __builtin_amdgcn_cvt_pkrtz(f.x, f.y);
    }
    __syncthreads();                                   // all waves done with wstage
  }
  const float bl = bias[lane];

  // XCD<->batch partition: blockIdx%8 -> XCD; one batch per 2 XCD slots.
  // xh batch slice = 4 MB -> resident in that XCD's 4 MB L2.
  const int xslot = blockIdx.x & 7;
  const int batch = xslot >> 1;                                // 0..3
  const int group = ((blockIdx.x >> 3) << 1) | (xslot & 1);    // 0..255
  const int wv    = group * WPB + wid;                         // 0..1023 in batch
  const float*  xb   = x   + (size_t)batch * (N_ * C_);
  const __fp16* xhb  = xh  + (size_t)batch * (N_ * C_);
  const int*    adjb = adj + (size_t)batch * N_ * K_;

  int idx[K_];                    // uniform -> SGPRs

  auto loadidx = [&](int n) {
    const int* ar = adjb + n * K_;                     // wave-uniform -> s_load
#pragma unroll
    for (int k = 0; k < K_; ++k) idx[k] = ar[k];
  };
  // 10 paired-row f16 DMAs (lanes 0-31 -> row 2d, lanes 32-63 -> row 2d+1,
  // LDS dest linear 256 B/chunk) + 1 f32 center-row DMA.  11 vm ops total.
  auto issue = [&](int n, int s) {
    auto ldsw = (__attribute__((address_space(3))) u32*)(&win[wid][s][0]);
#pragma unroll
    for (int d = 0; d < 10; ++d) {
      const int row = (lane < 32) ? idx[2 * d] : idx[2 * d + 1];
      const __fp16* src = xhb + row * C_ + (lane & 31) * 2;    // 4B aligned
      __builtin_amdgcn_global_load_lds(
          (const __attribute__((address_space(1))) u32*)src,
          ldsw + d * 64, 4, 0, 0);
    }
    const float* srcx = xb + n * C_ + lane;            // center row, f32-exact
    __builtin_amdgcn_global_load_lds(
        (const __attribute__((address_space(1))) u32*)srcx,
        ldsw + (K_ * C_ * 2) / 4, 4, 0, 0);
  };

  loadidx(wv);
  issue(wv, 0);
  loadidx(wv + WVB_F16);
  issue(wv + WVB_F16, 1);
  loadidx(wv + 2 * WVB_F16);

  const half2_t kOnes = {(__fp16)1.0f, (__fp16)1.0f};
  int cs = 0;                                          // compute stage (mod 3)
  for (int it = 0; it < CNT_F16; ++it) {
    const int n = wv + it * WVB_F16;

    if (it + 2 < CNT_F16) {
      int is = cs + 2; if (is >= STAGES) is -= STAGES;
      issue(n + 2 * WVB_F16, is);
      if (it + 3 < CNT_F16) loadidx(wv + (it + 3) * WVB_F16);
      // in-order VMEM return: if iter-it's last DMA were outstanding, the 22
      // newer DMAs would be too -> total >22 -> vmcnt(22) provably drains it.
      asm volatile("s_waitcnt vmcnt(22)" ::: "memory");
    } else if (it + 1 < CNT_F16) {
      asm volatile("s_waitcnt vmcnt(11)" ::: "memory");
    } else {
      asm volatile("s_waitcnt vmcnt(0)" ::: "memory");
    }
    __builtin_amdgcn_wave_barrier();

    // window sum: lane c reads f16 flat[20c..20c+19] as 5x ds_read_b64,
    // f32-accumulate via fdot2 with (1,1)
    const char* buf = reinterpret_cast<const char*>(&win[wid][cs][0]);
    const uint2* wq = reinterpret_cast<const uint2*>(buf + 40 * lane);  // 8B aligned
    float t0 = 0.f, t1 = 0.f;
#pragma unroll
    for (int s5 = 0; s5 < 5; ++s5) {
      const uint2 v = wq[s5];
      t0 = FDOT2(__builtin_bit_cast(half2_t, v.x), kOnes, t0);
      t1 = FDOT2(__builtin_bit_cast(half2_t, v.y), kOnes, t1);
    }
    const float xv = reinterpret_cast<const float*>(buf + K_ * C_ * 2)[lane];

    // pack edge vector to f16 once (lane packs pair v[2l],v[2l+1])
    fbuf[wid][lane]      = (t0 + t1) * (1.f / K_) - xv;        // a[c]
    fbuf[wid][C_ + lane] = xv;                                 // x[c]
    const float2 pr = reinterpret_cast<const float2*>(fbuf[wid])[lane];
    hbuf[wid][lane] = __builtin_bit_cast(u32, __builtin_amdgcn_cvt_pkrtz(pr.x, pr.y));

    // matvec: out[o] = sum_j edge[j]*W[o][j] via v_dot2_f32_f16
    float acc0 = 0.f, acc1 = 0.f, acc2 = 0.f, acc3 = 0.f;
    const uint4* hb = reinterpret_cast<const uint4*>(hbuf[wid]);
#pragma unroll
    for (int i = 0; i < 16; ++i) {
      const uint4 q = hb[i];
      acc0 = FDOT2(__builtin_bit_cast(half2_t, q.x), wp[4 * i + 0], acc0);
      acc1 = FDOT2(__builtin_bit_cast(half2_t, q.y), wp[4 * i + 1], acc1);
      acc2 = FDOT2(__builtin_bit_cast(half2_t, q.z), wp[4 * i + 2], acc2);
      acc3 = FDOT2(__builtin_bit_cast(half2_t, q.w), wp[4 * i + 3], acc3);
    }

    __builtin_nontemporal_store(((acc0 + acc1) + (acc2 + acc3)) + bl,
                                &out[((size_t)batch * N_ + n) * O_ + lane]);
    cs = cs + 1; if (cs >= STAGES) cs = 0;
  }
}

// ---------------------------------------------------------------- f32 fallback
// (previous proven kernel, used only if d_ws can't hold the 16 MB f16 shadow)
__global__ __launch_bounds__(BLOCK, 3) void edgeconv_f32_kernel(
    const float* __restrict__ x,
    const int*   __restrict__ adj,
    const float* __restrict__ W,
    const float* __restrict__ bias,
    float*       __restrict__ out)
{
  __shared__ __align__(16) float win2[WPB][2][WBUF];
  __shared__ __align__(16) float fbuf[WPB][2 * C_];
  __shared__ __align__(16) u32   hbuf[WPB][C_];

  const int lane = threadIdx.x & 63;
  const int wid  = __builtin_amdgcn_readfirstlane((int)(threadIdx.x >> 6));

  half2_t wp[64];
  {
    float* wstage = &win2[0][0][0];
    for (int i = threadIdx.x; i < O_ * 2 * C_; i += BLOCK)
      wstage[(i >> 7) * WROW + (i & 127)] = W[i];
    __syncthreads();
    const float2* wrow = reinterpret_cast<const float2*>(wstage + lane * WROW);
#pragma unroll
    for (int i = 0; i < 64; ++i) {
      const float2 f = wrow[i];
      wp[i] = __builtin_amdgcn_cvt_pkrtz(f.x, f.y);
    }
    __syncthreads();
  }
  const float bl = bias[lane];

  const int xslot = blockIdx.x & 7;
  const int batch = xslot >> 1;
  const int group = ((blockIdx.x >> 3) << 1) | (xslot & 1);
  const int wv    = group * WPB + wid;
  const int cnt   = (N_ - wv + WVB_F32 - 1) / WVB_F32;
  const float* xb   = x + (size_t)batch * (N_ * C_);
  const int*   adjb = adj + (size_t)batch * N_ * K_;

  int idx[K_];

  auto loadidx = [&](int n) {
    const int* ar = adjb + n * K_;
#pragma unroll
    for (int k = 0; k < K_; ++k) idx[k] = ar[k];
  };
  auto issue = [&](int n, int bsel) {
    auto ldsw = (__attribute__((address_space(3))) u32*)(&win2[wid][bsel][0]);
#pragma unroll
    for (int k = 0; k < K_; ++k) {
      const float* src = xb + idx[k] * C_ + lane;
      __builtin_amdgcn_global_load_lds(
          (const __attribute__((address_space(1))) u32*)src,
          ldsw + k * C_, 4, 0, 0);
    }
    const float* srcx = xb + n * C_ + lane;
    __builtin_amdgcn_global_load_lds(
        (const __attribute__((address_space(1))) u32*)srcx,
        ldsw + K_ * C_, 4, 0, 0);
  };

  loadidx(wv);
  issue(wv, 0);
  if (cnt > 1) loadidx(wv + WVB_F32);

  for (int it = 0; it < cnt; ++it) {
    const int n   = wv + it * WVB_F32;
    const int cur = it & 1;

    if (it + 1 < cnt) {
      issue(n + WVB_F32, cur ^ 1);
      asm volatile("s_waitcnt vmcnt(21)" ::: "memory");
    } else {
      asm volatile("s_waitcnt vmcnt(0)" ::: "memory");
    }
    __builtin_amdgcn_wave_barrier();

    if (it + 2 < cnt) loadidx(wv + (it + 2) * WVB_F32);

    const float* mywin = &win2[wid][cur][0];
    const float4* wq = reinterpret_cast<const float4*>(mywin + lane * K_);
    float t = 0.f;
#pragma unroll
    for (int s = 0; s < 5; ++s) {
      const float4 v = wq[s];
      t += (v.x + v.y) + (v.z + v.w);
    }
    const float xv = mywin[K_ * C_ + lane];

    fbuf[wid][lane]      = t * (1.f / K_) - xv;
    fbuf[wid][C_ + lane] = xv;
    const float2 pr = reinterpret_cast<const float2*>(fbuf[wid])[lane];
    hbuf[wid][lane] = __builtin_bit_cast(u32, __builtin_amdgcn_cvt_pkrtz(pr.x, pr.y));

    float acc0 = 0.f, acc1 = 0.f, acc2 = 0.f, acc3 = 0.f;
    const uint4* hb = reinterpret_cast<const uint4*>(hbuf[wid]);
#pragma unroll
    for (int i = 0; i < 16; ++i) {
      const uint4 q = hb[i];
      acc0 = FDOT2(__builtin_bit_cast(half2_t, q.x), wp[4 * i + 0], acc0);
      acc1 = FDOT2(__builtin_bit_cast(half2_t, q.y), wp[4 * i + 1], acc1);
      acc2 = FDOT2(__builtin_bit_cast(half2_t, q.z), wp[4 * i + 2], acc2);
      acc3 = FDOT2(__builtin_bit_cast(half2_t, q.w), wp[4 * i + 3], acc3);
    }

    out[((size_t)batch * N_ + n) * O_ + lane] = ((acc0 + acc1) + (acc2 + acc3)) + bl;
  }
}

extern "C" void kernel_launch(void* const* d_in, const int* in_sizes, int n_in,
                              void* d_out, int out_size, void* d_ws, size_t ws_size,
                              hipStream_t stream) {
  const float* x    = (const float*)d_in[0];
  const int*   adj  = (const int*)d_in[1];
  const float* W    = (const float*)d_in[2];
  const float* bias = (const float*)d_in[3];
  float* out = (float*)d_out;

  const size_t need = (size_t)4 * N_ * C_ * sizeof(__fp16);   // 16 MB
  if (d_ws != nullptr && ws_size >= need) {
    __fp16* xh = (__fp16*)d_ws;
    hipLaunchKernelGGL(cvt_f16_kernel, dim3((4 * N_ * C_) / (4 * BLOCK)), dim3(BLOCK),
                       0, stream, x, xh);
    hipLaunchKernelGGL(edgeconv_f16_kernel, dim3(GRID_F16), dim3(BLOCK), 0, stream,
                       x, xh, adj, W, bias, out);
  } else {
    hipLaunchKernelGGL(edgeconv_f32_kernel, dim3(GRID_F32), dim3(BLOCK), 0, stream,
                       x, adj, W, bias, out);
  }
}